// Round 1
// baseline (632.393 us; speedup 1.0000x reference)
//
#include <hip/hip_runtime.h>
#include <math.h>

// Problem constants
#define BB 2
#define LL 2048
#define DD 2048
#define HH 16
#define KVH 8
#define HDIM 128
#define REP (HH / KVH)
#define SCALE_F 0.08838834764831845f   // 128^-0.5
#define EPS_F 1e-5f

typedef unsigned short u16;
typedef __attribute__((ext_vector_type(8))) short short8;
typedef __attribute__((ext_vector_type(4))) float f32x4;

#define MFMA16(a, b, c) __builtin_amdgcn_mfma_f32_16x16x32_bf16((a), (b), (c), 0, 0, 0)

__device__ __forceinline__ float b2f(u16 u) {
    union { unsigned int i; float f; } x;
    x.i = ((unsigned int)u) << 16;
    return x.f;
}
__device__ __forceinline__ u16 f2b(float f) {
    unsigned int x = __float_as_uint(f);
    unsigned int r = x + 0x7FFFu + ((x >> 16) & 1u);   // round-to-nearest-even
    return (u16)(r >> 16);
}

// ---------------------------------------------------------------------------
// fp32 -> bf16 convert (for x)
// ---------------------------------------------------------------------------
__global__ __launch_bounds__(256) void convert_f32_bf16(const float* __restrict__ in,
                                                        u16* __restrict__ out, int n) {
    int i = (blockIdx.x * 256 + threadIdx.x) * 4;
    if (i >= n) return;
    float4 v = *(const float4*)(in + i);
    unsigned int p0 = (unsigned int)f2b(v.x) | ((unsigned int)f2b(v.y) << 16);
    unsigned int p1 = (unsigned int)f2b(v.z) | ((unsigned int)f2b(v.w) << 16);
    uint2 pk; pk.x = p0; pk.y = p1;
    *(uint2*)(out + i) = pk;
}

// ---------------------------------------------------------------------------
// fp32 [R][C] -> bf16 transposed [C][R]
// ---------------------------------------------------------------------------
__global__ __launch_bounds__(256) void transpose_conv(const float* __restrict__ in,
                                                      u16* __restrict__ out, int R, int C) {
    __shared__ u16 t[64 * 65];
    int c0 = blockIdx.x * 64, r0 = blockIdx.y * 64;
#pragma unroll
    for (int i = 0; i < 16; i++) {
        int idx = threadIdx.x + i * 256;
        int r = idx >> 6, c = idx & 63;
        t[r * 65 + c] = f2b(in[(size_t)(r0 + r) * C + c0 + c]);
    }
    __syncthreads();
#pragma unroll
    for (int i = 0; i < 16; i++) {
        int idx = threadIdx.x + i * 256;
        int r = idx >> 6, c = idx & 63;
        out[(size_t)(c0 + r) * R + r0 + c] = t[c * 65 + r];
    }
}

// ---------------------------------------------------------------------------
// RoPE cos/sin tables, matching numpy fp32 semantics:
//   freq  = correctly-rounded fp32 of 10000^(d/64)   (double pow -> fp32)
//   angle = fp32(pos) * freq                         (fp32 multiply, bit-exact)
//   cos/sin = correctly rounded of that fp32 angle   (double eval -> fp32)
// ---------------------------------------------------------------------------
__global__ __launch_bounds__(256) void rope_table(float* __restrict__ ct, float* __restrict__ st) {
    int i = blockIdx.x * 256 + threadIdx.x;   // i < LL*64
    int pos = i >> 6, d = i & 63;
    float freq = (float)pow(10000.0, (double)d * (1.0 / 64.0));
    float ang = (float)pos * freq;
    double a = (double)ang;
    ct[i] = (float)cos(a);
    st[i] = (float)sin(a);
}

// ---------------------------------------------------------------------------
// GEMM: C[M,N] = A[M,K] @ Bt[N,K]^T   (bf16 in, bf16 or fp32 out)
// 128x128 tile, BK=32, 256 threads = 4 waves, each wave 64x64.
// ---------------------------------------------------------------------------
template <bool F32OUT>
__global__ __launch_bounds__(256) void gemm_bt(const u16* __restrict__ A,
                                               const u16* __restrict__ Bt,
                                               void* __restrict__ Cv, int M, int N, int K) {
    __shared__ u16 As[128 * 40];   // stride 40 elems = 80B (16B aligned rows)
    __shared__ u16 Bs[128 * 40];
    const int tid = threadIdx.x;
    const int w = tid >> 6, lane = tid & 63;
    const int lm = lane & 15, lq = lane >> 4;
    const int bn0 = blockIdx.x * 128, bm0 = blockIdx.y * 128;
    const int wm = (w >> 1) * 64, wn = (w & 1) * 64;

    f32x4 acc[4][4];
#pragma unroll
    for (int i = 0; i < 4; i++)
#pragma unroll
        for (int j = 0; j < 4; j++) acc[i][j] = (f32x4){0.f, 0.f, 0.f, 0.f};

    for (int k0 = 0; k0 < K; k0 += 32) {
        __syncthreads();
#pragma unroll
        for (int i = 0; i < 2; i++) {
            int c = tid + i * 256;        // 512 chunks of 8 elems
            int r = c >> 2, cc = c & 3;
            *(short8*)(&As[r * 40 + cc * 8]) =
                *(const short8*)(A + (size_t)(bm0 + r) * K + k0 + cc * 8);
            *(short8*)(&Bs[r * 40 + cc * 8]) =
                *(const short8*)(Bt + (size_t)(bn0 + r) * K + k0 + cc * 8);
        }
        __syncthreads();

        short8 af[4], bf[4];
#pragma unroll
        for (int mt = 0; mt < 4; mt++)
            af[mt] = *(const short8*)(&As[(wm + mt * 16 + lm) * 40 + lq * 8]);
#pragma unroll
        for (int nt = 0; nt < 4; nt++)
            bf[nt] = *(const short8*)(&Bs[(wn + nt * 16 + lm) * 40 + lq * 8]);
#pragma unroll
        for (int mt = 0; mt < 4; mt++)
#pragma unroll
            for (int nt = 0; nt < 4; nt++) acc[mt][nt] = MFMA16(af[mt], bf[nt], acc[mt][nt]);
    }

#pragma unroll
    for (int mt = 0; mt < 4; mt++)
#pragma unroll
        for (int nt = 0; nt < 4; nt++)
#pragma unroll
            for (int r = 0; r < 4; r++) {
                int row = bm0 + wm + mt * 16 + lq * 4 + r;
                int col = bn0 + wn + nt * 16 + lm;
                if (F32OUT)
                    ((float*)Cv)[(size_t)row * N + col] = acc[mt][nt][r];
                else
                    ((u16*)Cv)[(size_t)row * N + col] = f2b(acc[mt][nt][r]);
            }
}

// ---------------------------------------------------------------------------
// Fused RoPE + RMSNorm, in-place on q and k. One wave per (row, head-slot).
// ---------------------------------------------------------------------------
__global__ __launch_bounds__(256) void rope_norm(u16* __restrict__ q, u16* __restrict__ k,
                                                 const float* __restrict__ qw,
                                                 const float* __restrict__ kw,
                                                 const float* __restrict__ ct,
                                                 const float* __restrict__ st) {
    int slot = blockIdx.x * 4 + (threadIdx.x >> 6);
    int lane = threadIdx.x & 63;
    int hh = slot % (HH + KVH);
    int row = slot / (HH + KVH);   // [0, B*L)
    int pos = row & (LL - 1);

    u16* base;
    const float* w;
    if (hh < HH) { base = q + (size_t)row * (HH * HDIM) + hh * HDIM; w = qw; }
    else         { base = k + (size_t)row * (KVH * HDIM) + (hh - HH) * HDIM; w = kw; }

    float x1 = b2f(base[lane]), x2 = b2f(base[lane + 64]);
    float c = ct[pos * 64 + lane], s = st[pos * 64 + lane];
    float r1 = x1 * c - x2 * s;
    float r2 = x2 * c + x1 * s;
    float ss = r1 * r1 + r2 * r2;
#pragma unroll
    for (int m = 1; m < 64; m <<= 1) ss += __shfl_xor(ss, m, 64);
    float sc = 1.0f / sqrtf(ss * (1.0f / 128.0f) + EPS_F);
    base[lane] = f2b(r1 * sc * w[lane]);
    base[lane + 64] = f2b(r2 * sc * w[lane + 64]);
}

// ---------------------------------------------------------------------------
// Flash attention (non-causal, full softmax over L keys).
// Block: 256 threads (4 waves). Block handles (b, h, 64 q-rows); each wave 16 rows.
// K-tile of 128 keys staged [key][dim]; V staged transposed [dim][key] into the
// SAME LDS buffer (3 barriers per tile keeps static LDS < 64KB).
// ---------------------------------------------------------------------------
__global__ __launch_bounds__(256) void attn_kernel(const u16* __restrict__ qb,
                                                   const u16* __restrict__ kb,
                                                   const u16* __restrict__ vb,
                                                   u16* __restrict__ ob) {
    __shared__ u16 KV[128 * 136];        // K tile then V^T tile (stride 136)
    __shared__ u16 Ps[4 * 16 * 136];     // per-wave P staging [16 rows][128 keys]

    const int tid = threadIdx.x, w = tid >> 6, lane = tid & 63;
    const int lm = lane & 15, lq = lane >> 4;
    const int q0 = blockIdx.x * 64;
    const int bh = blockIdx.y, b = bh >> 4, h = bh & 15, g = h >> 1;   // rep=2 -> kv head h/2

    const u16* kbase = kb + (size_t)b * LL * (KVH * HDIM) + g * HDIM;
    const u16* vbase = vb + (size_t)b * LL * (KVH * HDIM) + g * HDIM;

    // Q fragments held for the whole kernel (A-layout: A[m=lm][k=lq*8+j])
    short8 aq[4];
    {
        size_t qoff = (size_t)(b * LL + q0 + w * 16 + lm) * (HH * HDIM) + h * HDIM + lq * 8;
#pragma unroll
        for (int kk = 0; kk < 4; kk++) aq[kk] = *(const short8*)(qb + qoff + kk * 32);
    }

    f32x4 o[8];
#pragma unroll
    for (int i = 0; i < 8; i++) o[i] = (f32x4){0.f, 0.f, 0.f, 0.f};
    float mrow[4] = {-1e30f, -1e30f, -1e30f, -1e30f};
    float lrow[4] = {0.f, 0.f, 0.f, 0.f};

    for (int t = 0; t < LL / 128; t++) {
        __syncthreads();   // prior PV reads done before restaging
        // stage K tile [128 keys][128 dims]
#pragma unroll
        for (int i = 0; i < 8; i++) {
            int c = tid + i * 256;
            int r = c >> 4, cc = c & 15;
            *(short8*)(&KV[r * 136 + cc * 8]) =
                *(const short8*)(kbase + (size_t)(t * 128 + r) * (KVH * HDIM) + cc * 8);
        }
        __syncthreads();

        // S = Q @ K^T  (8 n-tiles of 16 keys)
        f32x4 s[8];
#pragma unroll
        for (int nt = 0; nt < 8; nt++) {
            s[nt] = (f32x4){0.f, 0.f, 0.f, 0.f};
#pragma unroll
            for (int kk = 0; kk < 4; kk++) {
                short8 bf = *(const short8*)(&KV[(nt * 16 + lm) * 136 + kk * 32 + lq * 8]);
                s[nt] = MFMA16(aq[kk], bf, s[nt]);
            }
        }

        // scale + tile row max
        float tm[4] = {-1e30f, -1e30f, -1e30f, -1e30f};
#pragma unroll
        for (int nt = 0; nt < 8; nt++)
#pragma unroll
            for (int r = 0; r < 4; r++) {
                s[nt][r] *= SCALE_F;
                tm[r] = fmaxf(tm[r], s[nt][r]);
            }
#pragma unroll
        for (int m = 1; m < 16; m <<= 1)
#pragma unroll
            for (int r = 0; r < 4; r++) tm[r] = fmaxf(tm[r], __shfl_xor(tm[r], m, 64));

        float mn[4], al[4], ps[4];
#pragma unroll
        for (int r = 0; r < 4; r++) {
            mn[r] = fmaxf(mrow[r], tm[r]);
            al[r] = expf(mrow[r] - mn[r]);
            ps[r] = 0.f;
        }

        // P = exp(s - mn): accumulate row sums, stage bf16 P in LDS (C-layout -> A-layout)
#pragma unroll
        for (int nt = 0; nt < 8; nt++)
#pragma unroll
            for (int r = 0; r < 4; r++) {
                float p = expf(s[nt][r] - mn[r]);
                ps[r] += p;
                Ps[(w * 16 + lq * 4 + r) * 136 + nt * 16 + lm] = f2b(p);
            }
#pragma unroll
        for (int m = 1; m < 16; m <<= 1)
#pragma unroll
            for (int r = 0; r < 4; r++) ps[r] += __shfl_xor(ps[r], m, 64);

#pragma unroll
        for (int r = 0; r < 4; r++) {
            lrow[r] = lrow[r] * al[r] + ps[r];
            mrow[r] = mn[r];
        }
#pragma unroll
        for (int dn = 0; dn < 8; dn++)
#pragma unroll
            for (int r = 0; r < 4; r++) o[dn][r] *= al[r];

        __syncthreads();   // all waves done reading K
        // stage V transposed: KV[dim][key]
#pragma unroll
        for (int i = 0; i < 4; i++) {
            int c = tid + i * 256;
            int kp = c >> 4, dc = c & 15;   // key pair, dim chunk
            const u16* src = vbase + (size_t)(t * 128 + kp * 2) * (KVH * HDIM) + dc * 8;
            short8 v0 = *(const short8*)src;
            short8 v1 = *(const short8*)(src + KVH * HDIM);
#pragma unroll
            for (int j = 0; j < 8; j++) {
                unsigned int pk = (unsigned int)(u16)v0[j] | ((unsigned int)(u16)v1[j] << 16);
                *(unsigned int*)(&KV[(dc * 8 + j) * 136 + kp * 2]) = pk;
            }
        }
        __syncthreads();

        // O += P @ V   (8 dim n-tiles)
#pragma unroll
        for (int kk = 0; kk < 4; kk++) {
            short8 pa = *(const short8*)(&Ps[(w * 16 + lm) * 136 + kk * 32 + lq * 8]);
#pragma unroll
            for (int dn = 0; dn < 8; dn++) {
                short8 bv = *(const short8*)(&KV[(dn * 16 + lm) * 136 + kk * 32 + lq * 8]);
                o[dn] = MFMA16(pa, bv, o[dn]);
            }
        }
    }

    float inv[4];
#pragma unroll
    for (int r = 0; r < 4; r++) inv[r] = 1.0f / lrow[r];
    size_t obase = (size_t)(b * LL + q0 + w * 16 + lq * 4) * (HH * HDIM) + h * HDIM;
#pragma unroll
    for (int dn = 0; dn < 8; dn++)
#pragma unroll
        for (int r = 0; r < 4; r++)
            ob[obase + (size_t)r * (HH * HDIM) + dn * 16 + lm] = f2b(o[dn][r] * inv[r]);
}

// ---------------------------------------------------------------------------
extern "C" void kernel_launch(void* const* d_in, const int* in_sizes, int n_in,
                              void* d_out, int out_size, void* d_ws, size_t ws_size,
                              hipStream_t stream) {
    const float* x  = (const float*)d_in[0];
    const float* wq = (const float*)d_in[1];
    const float* wk = (const float*)d_in[2];
    const float* wv = (const float*)d_in[3];
    const float* wo = (const float*)d_in[4];
    const float* qn = (const float*)d_in[5];
    const float* kn = (const float*)d_in[6];

    u16* ws = (u16*)d_ws;
    const size_t SZ_X = (size_t)BB * LL * DD;           // 8388608
    const size_t SZ_K = (size_t)BB * LL * KVH * HDIM;   // 4194304
    // layout (elements). att reuses xb's buffer (xb dead after QKV GEMMs).
    u16* xb  = ws;                    // SZ_X   (also att)
    u16* q   = xb  + SZ_X;            // SZ_X
    u16* k   = q   + SZ_X;            // SZ_K
    u16* v   = k   + SZ_K;            // SZ_K
    u16* wqT = v   + SZ_K;            // 2048*2048
    u16* wkT = wqT + (size_t)DD * DD; // 1024*2048
    u16* wvT = wkT + (size_t)DD * DD / 2;
    u16* woT = wvT + (size_t)DD * DD / 2;
    float* ct = (float*)(woT + (size_t)DD * DD);   // LL*64 floats
    float* st = ct + (size_t)LL * 64;
    u16* att = xb;

    // 1. convert x -> bf16
    convert_f32_bf16<<<dim3((unsigned)(SZ_X / 1024)), dim3(256), 0, stream>>>(x, xb, (int)SZ_X);
    // 2. transpose+convert weights
    transpose_conv<<<dim3(32, 32), dim3(256), 0, stream>>>(wq, wqT, DD, DD);
    transpose_conv<<<dim3(16, 32), dim3(256), 0, stream>>>(wk, wkT, DD, KVH * HDIM);
    transpose_conv<<<dim3(16, 32), dim3(256), 0, stream>>>(wv, wvT, DD, KVH * HDIM);
    transpose_conv<<<dim3(32, 32), dim3(256), 0, stream>>>(wo, woT, HH * HDIM, DD);
    // 3. rope tables
    rope_table<<<dim3(LL * 64 / 256), dim3(256), 0, stream>>>(ct, st);
    // 4. QKV projections
    gemm_bt<false><<<dim3(DD / 128, BB * LL / 128), dim3(256), 0, stream>>>(xb, wqT, q, BB * LL, DD, DD);
    gemm_bt<false><<<dim3(KVH * HDIM / 128, BB * LL / 128), dim3(256), 0, stream>>>(xb, wkT, k, BB * LL, KVH * HDIM, DD);
    gemm_bt<false><<<dim3(KVH * HDIM / 128, BB * LL / 128), dim3(256), 0, stream>>>(xb, wvT, v, BB * LL, KVH * HDIM, DD);
    // 5. fused RoPE + RMSNorm on q, k (in place)
    rope_norm<<<dim3(BB * LL * (HH + KVH) / 4), dim3(256), 0, stream>>>(q, k, qn, kn, ct, st);
    // 6. attention -> att (reuses xb buffer)
    attn_kernel<<<dim3(LL / 64, BB * HH), dim3(256), 0, stream>>>(q, k, v, att);
    // 7. output projection -> d_out (fp32)
    gemm_bt<true><<<dim3(DD / 128, BB * LL / 128), dim3(256), 0, stream>>>(att, woT, d_out, BB * LL, DD, DD);
}

// Round 2
// 509.327 us; speedup vs baseline: 1.2416x; 1.2416x over previous
//
#include <hip/hip_runtime.h>
#include <math.h>

// Problem constants
#define BB 2
#define LL 2048
#define DD 2048
#define HH 16
#define KVH 8
#define HDIM 128
#define SCALE_F 0.08838834764831845f   // 128^-0.5
#define EPS_F 1e-5f
#define LOG2E 1.4426950408889634f

typedef unsigned short u16;
typedef __attribute__((ext_vector_type(8))) short short8;
typedef __attribute__((ext_vector_type(4))) float f32x4;

#define MFMA16(a, b, c) __builtin_amdgcn_mfma_f32_16x16x32_bf16((a), (b), (c), 0, 0, 0)

__device__ __forceinline__ float b2f(u16 u) {
    union { unsigned int i; float f; } x;
    x.i = ((unsigned int)u) << 16;
    return x.f;
}
__device__ __forceinline__ u16 f2b(float f) {
    unsigned int x = __float_as_uint(f);
    unsigned int r = x + 0x7FFFu + ((x >> 16) & 1u);   // round-to-nearest-even
    return (u16)(r >> 16);
}
// async global->LDS, 16B per lane; LDS dest = base + lane*16 (HW-fixed)
__device__ __forceinline__ void g2l(const u16* g, u16* l) {
    __builtin_amdgcn_global_load_lds(
        (const __attribute__((address_space(1))) unsigned int*)g,
        (__attribute__((address_space(3))) unsigned int*)l, 16, 0, 0);
}

// ---------------------------------------------------------------------------
// fp32 -> bf16 convert (for x)
// ---------------------------------------------------------------------------
__global__ __launch_bounds__(256) void convert_f32_bf16(const float* __restrict__ in,
                                                        u16* __restrict__ out, int n) {
    int i = (blockIdx.x * 256 + threadIdx.x) * 4;
    if (i >= n) return;
    float4 v = *(const float4*)(in + i);
    unsigned int p0 = (unsigned int)f2b(v.x) | ((unsigned int)f2b(v.y) << 16);
    unsigned int p1 = (unsigned int)f2b(v.z) | ((unsigned int)f2b(v.w) << 16);
    uint2 pk; pk.x = p0; pk.y = p1;
    *(uint2*)(out + i) = pk;
}

// ---------------------------------------------------------------------------
// fp32 [R][C] -> bf16 transposed [C][R]
// ---------------------------------------------------------------------------
__global__ __launch_bounds__(256) void transpose_conv(const float* __restrict__ in,
                                                      u16* __restrict__ out, int R, int C) {
    __shared__ u16 t[64 * 65];
    int c0 = blockIdx.x * 64, r0 = blockIdx.y * 64;
#pragma unroll
    for (int i = 0; i < 16; i++) {
        int idx = threadIdx.x + i * 256;
        int r = idx >> 6, c = idx & 63;
        t[r * 65 + c] = f2b(in[(size_t)(r0 + r) * C + c0 + c]);
    }
    __syncthreads();
#pragma unroll
    for (int i = 0; i < 16; i++) {
        int idx = threadIdx.x + i * 256;
        int r = idx >> 6, c = idx & 63;
        out[(size_t)(c0 + r) * R + r0 + c] = t[c * 65 + r];
    }
}

// ---------------------------------------------------------------------------
// bf16 V [b][l][g][d] -> vt [b*8+g][d][l]
// ---------------------------------------------------------------------------
__global__ __launch_bounds__(256) void transpose_v(const u16* __restrict__ v,
                                                   u16* __restrict__ vt) {
    __shared__ u16 t[64 * 65];
    int l0 = blockIdx.x * 64, d0 = blockIdx.y * 64;
    int bg = blockIdx.z, b = bg >> 3, g = bg & 7;
    const u16* src = v + (size_t)b * LL * (KVH * HDIM) + g * HDIM;
    u16* dst = vt + (size_t)bg * HDIM * LL;
#pragma unroll
    for (int i = 0; i < 16; i++) {
        int idx = threadIdx.x + i * 256;
        int r = idx >> 6, c = idx & 63;
        t[r * 65 + c] = src[(size_t)(l0 + r) * (KVH * HDIM) + d0 + c];
    }
    __syncthreads();
#pragma unroll
    for (int i = 0; i < 16; i++) {
        int idx = threadIdx.x + i * 256;
        int r = idx >> 6, c = idx & 63;   // r = dim, c = key
        dst[(size_t)(d0 + r) * LL + l0 + c] = t[c * 65 + r];
    }
}

// ---------------------------------------------------------------------------
// RoPE cos/sin tables (numpy fp32 semantics)
// ---------------------------------------------------------------------------
__global__ __launch_bounds__(256) void rope_table(float* __restrict__ ct, float* __restrict__ st) {
    int i = blockIdx.x * 256 + threadIdx.x;   // i < LL*64
    int pos = i >> 6, d = i & 63;
    float freq = (float)pow(10000.0, (double)d * (1.0 / 64.0));
    float ang = (float)pos * freq;
    double a = (double)ang;
    ct[i] = (float)cos(a);
    st[i] = (float)sin(a);
}

// ---------------------------------------------------------------------------
// GEMM: C[M,N] = A[M,K] @ Bt[N,K]^T, m97 structure: global_load_lds width=16,
// unpadded 32-elem rows (conflict-free at 64B row stride), 128x128 tile.
// ---------------------------------------------------------------------------
template <bool F32OUT>
__global__ __launch_bounds__(256) void gemm_bt(const u16* __restrict__ A,
                                               const u16* __restrict__ Bt,
                                               void* __restrict__ Cv, int M, int N, int K) {
    __shared__ __align__(16) u16 As[128 * 32];
    __shared__ __align__(16) u16 Bs[128 * 32];
    const int tid = threadIdx.x;
    const int w = tid >> 6, lane = tid & 63;
    const int lm = lane & 15, lq = lane >> 4;
    const int bn0 = blockIdx.x * 128, bm0 = blockIdx.y * 128;
    const int wm = (w >> 1) * 64, wn = (w & 1) * 64;

    f32x4 acc[4][4];
#pragma unroll
    for (int i = 0; i < 4; i++)
#pragma unroll
        for (int j = 0; j < 4; j++) acc[i][j] = (f32x4){0.f, 0.f, 0.f, 0.f};

    // staging addresses: wave w stages tile rows [w*32, w*32+32)
    const int sr = w * 32 + (lane >> 2);     // + 16 for second chunk
    const int scc = lane & 3;
    const u16* ga = A + (size_t)(bm0 + sr) * K + scc * 8;
    const u16* gb = Bt + (size_t)(bn0 + sr) * K + scc * 8;
    u16* lA = &As[w * 1024];
    u16* lB = &Bs[w * 1024];

    for (int k0 = 0; k0 < K; k0 += 32) {
        __syncthreads();
        g2l(ga + k0, lA);
        g2l(ga + (size_t)16 * K + k0, lA + 512);
        g2l(gb + k0, lB);
        g2l(gb + (size_t)16 * K + k0, lB + 512);
        __syncthreads();

        short8 af[4], bf[4];
#pragma unroll
        for (int mt = 0; mt < 4; mt++)
            af[mt] = *(const short8*)(&As[(wm + mt * 16 + lm) * 32 + lq * 8]);
#pragma unroll
        for (int nt = 0; nt < 4; nt++)
            bf[nt] = *(const short8*)(&Bs[(wn + nt * 16 + lm) * 32 + lq * 8]);
#pragma unroll
        for (int mt = 0; mt < 4; mt++)
#pragma unroll
            for (int nt = 0; nt < 4; nt++) acc[mt][nt] = MFMA16(af[mt], bf[nt], acc[mt][nt]);
    }

#pragma unroll
    for (int mt = 0; mt < 4; mt++)
#pragma unroll
        for (int nt = 0; nt < 4; nt++)
#pragma unroll
            for (int r = 0; r < 4; r++) {
                int row = bm0 + wm + mt * 16 + lq * 4 + r;
                int col = bn0 + wn + nt * 16 + lm;
                if (F32OUT)
                    ((float*)Cv)[(size_t)row * N + col] = acc[mt][nt][r];
                else
                    ((u16*)Cv)[(size_t)row * N + col] = f2b(acc[mt][nt][r]);
            }
}

// ---------------------------------------------------------------------------
// Fused RoPE + RMSNorm, in-place on q and k. One wave per (row, head-slot).
// ---------------------------------------------------------------------------
__global__ __launch_bounds__(256) void rope_norm(u16* __restrict__ q, u16* __restrict__ k,
                                                 const float* __restrict__ qw,
                                                 const float* __restrict__ kw,
                                                 const float* __restrict__ ct,
                                                 const float* __restrict__ st) {
    int slot = blockIdx.x * 4 + (threadIdx.x >> 6);
    int lane = threadIdx.x & 63;
    int hh = slot % (HH + KVH);
    int row = slot / (HH + KVH);   // [0, B*L)
    int pos = row & (LL - 1);

    u16* base;
    const float* w;
    if (hh < HH) { base = q + (size_t)row * (HH * HDIM) + hh * HDIM; w = qw; }
    else         { base = k + (size_t)row * (KVH * HDIM) + (hh - HH) * HDIM; w = kw; }

    float x1 = b2f(base[lane]), x2 = b2f(base[lane + 64]);
    float c = ct[pos * 64 + lane], s = st[pos * 64 + lane];
    float r1 = x1 * c - x2 * s;
    float r2 = x2 * c + x1 * s;
    float ss = r1 * r1 + r2 * r2;
#pragma unroll
    for (int m = 1; m < 64; m <<= 1) ss += __shfl_xor(ss, m, 64);
    float sc = 1.0f / sqrtf(ss * (1.0f / 128.0f) + EPS_F);
    base[lane] = f2b(r1 * sc * w[lane]);
    base[lane + 64] = f2b(r2 * sc * w[lane + 64]);
}

// ---------------------------------------------------------------------------
// Flash attention (non-causal). Block = 256 threads (4 waves) = 64 q-rows.
// K tile [key][dim] and V^T tile [dim][key] staged into the SAME 32KB LDS
// buffer via global_load_lds w/ XOR granule swizzle (rows unpadded 256B).
// P round-trips through padded Ps LDS (wave-private, no barrier needed).
// ---------------------------------------------------------------------------
__global__ __launch_bounds__(256) void attn_kernel(const u16* __restrict__ qb,
                                                   const u16* __restrict__ kb,
                                                   const u16* __restrict__ vt,
                                                   u16* __restrict__ ob) {
    __shared__ __align__(16) u16 Kt[128 * 128];     // K tile, then V^T tile
    __shared__ __align__(16) u16 Ps[4 * 16 * 136];  // per-wave P staging

    const int tid = threadIdx.x, w = tid >> 6, lane = tid & 63;
    const int lm = lane & 15, lq = lane >> 4;
    const int q0 = blockIdx.x * 64;
    const int bh = blockIdx.y, b = bh >> 4, hd = bh & 15, g = hd >> 1;

    const u16* kbase = kb + (size_t)b * LL * (KVH * HDIM) + g * HDIM;
    const u16* vtbase = vt + (size_t)(b * KVH + g) * HDIM * LL;

    // staging pattern: wave w stages rows [w*32, w*32+32) in 8 chunks of 4 rows
    const int srow = (lane >> 4);       // 0..3 within chunk
    const int scc = lane & 15;          // granule 0..15

    // Q fragments (A-layout: A[m=lm][k=lq*8+j])
    short8 aq[4];
    {
        size_t qoff = (size_t)(b * LL + q0 + w * 16 + lm) * (HH * HDIM) + hd * HDIM + lq * 8;
#pragma unroll
        for (int kk = 0; kk < 4; kk++) aq[kk] = *(const short8*)(qb + qoff + kk * 32);
    }

    f32x4 o[8];
#pragma unroll
    for (int i = 0; i < 8; i++) o[i] = (f32x4){0.f, 0.f, 0.f, 0.f};
    float mrow[4] = {-1e30f, -1e30f, -1e30f, -1e30f};
    float lrow[4] = {0.f, 0.f, 0.f, 0.f};
    const float SC2 = SCALE_F * LOG2E;   // fold into log2 domain: exp2 path

    for (int t = 0; t < LL / 128; t++) {
        __syncthreads();   // prior PV fragment reads done before restaging
        // stage K tile [128 keys][128 dims], XOR-swizzled granules
#pragma unroll
        for (int ch = 0; ch < 8; ch++) {
            int r = (w * 8 + ch) * 4 + srow;
            int gc = scc ^ (r & 15);
            g2l(kbase + (size_t)(t * 128 + r) * (KVH * HDIM) + gc * 8,
                &Kt[(w * 8 + ch) * 512]);
        }
        __syncthreads();

        // S = Q @ K^T
        f32x4 s[8];
#pragma unroll
        for (int nt = 0; nt < 8; nt++) {
            s[nt] = (f32x4){0.f, 0.f, 0.f, 0.f};
#pragma unroll
            for (int kk = 0; kk < 4; kk++) {
                int r = nt * 16 + lm;
                int gg = (kk * 4 + lq) ^ (r & 15);
                short8 bf = *(const short8*)(&Kt[r * 128 + gg * 8]);
                s[nt] = MFMA16(aq[kk], bf, s[nt]);
            }
        }

        // scale (log2 domain) + tile row max
        float tm[4] = {-1e30f, -1e30f, -1e30f, -1e30f};
#pragma unroll
        for (int nt = 0; nt < 8; nt++)
#pragma unroll
            for (int r = 0; r < 4; r++) {
                s[nt][r] *= SC2;
                tm[r] = fmaxf(tm[r], s[nt][r]);
            }
#pragma unroll
        for (int m = 1; m < 16; m <<= 1)
#pragma unroll
            for (int r = 0; r < 4; r++) tm[r] = fmaxf(tm[r], __shfl_xor(tm[r], m, 64));

        float mn[4], al[4], psum[4];
#pragma unroll
        for (int r = 0; r < 4; r++) {
            mn[r] = fmaxf(mrow[r], tm[r]);
            al[r] = exp2f(mrow[r] - mn[r]);
            psum[r] = 0.f;
        }

        // P = exp2(s - mn), stage bf16 P in wave-private LDS (C-layout -> A-layout)
#pragma unroll
        for (int nt = 0; nt < 8; nt++)
#pragma unroll
            for (int r = 0; r < 4; r++) {
                float p = exp2f(s[nt][r] - mn[r]);
                psum[r] += p;
                Ps[(w * 16 + lq * 4 + r) * 136 + nt * 16 + lm] = f2b(p);
            }
#pragma unroll
        for (int m = 1; m < 16; m <<= 1)
#pragma unroll
            for (int r = 0; r < 4; r++) psum[r] += __shfl_xor(psum[r], m, 64);

#pragma unroll
        for (int r = 0; r < 4; r++) {
            lrow[r] = lrow[r] * al[r] + psum[r];
            mrow[r] = mn[r];
        }
#pragma unroll
        for (int dn = 0; dn < 8; dn++)
#pragma unroll
            for (int r = 0; r < 4; r++) o[dn][r] *= al[r];

        __syncthreads();   // all waves done reading K
        // stage V^T tile [128 dims][128 keys] from pre-transposed vt
#pragma unroll
        for (int ch = 0; ch < 8; ch++) {
            int r = (w * 8 + ch) * 4 + srow;
            int gc = scc ^ (r & 15);
            g2l(vtbase + (size_t)r * LL + t * 128 + gc * 8,
                &Kt[(w * 8 + ch) * 512]);
        }
        __syncthreads();

        // O += P @ V
#pragma unroll
        for (int kk = 0; kk < 4; kk++) {
            short8 pa = *(const short8*)(&Ps[(w * 16 + lm) * 136 + kk * 32 + lq * 8]);
#pragma unroll
            for (int dn = 0; dn < 8; dn++) {
                int r = dn * 16 + lm;
                int gg = (kk * 4 + lq) ^ (r & 15);
                short8 bv = *(const short8*)(&Kt[r * 128 + gg * 8]);
                o[dn] = MFMA16(pa, bv, o[dn]);
            }
        }
    }

    float inv[4];
#pragma unroll
    for (int r = 0; r < 4; r++) inv[r] = 1.0f / lrow[r];
    size_t obase = (size_t)(b * LL + q0 + w * 16 + lq * 4) * (HH * HDIM) + hd * HDIM;
#pragma unroll
    for (int dn = 0; dn < 8; dn++)
#pragma unroll
        for (int r = 0; r < 4; r++)
            ob[obase + (size_t)r * (HH * HDIM) + dn * 16 + lm] = f2b(o[dn][r] * inv[r]);
}

// ---------------------------------------------------------------------------
extern "C" void kernel_launch(void* const* d_in, const int* in_sizes, int n_in,
                              void* d_out, int out_size, void* d_ws, size_t ws_size,
                              hipStream_t stream) {
    const float* x  = (const float*)d_in[0];
    const float* wq = (const float*)d_in[1];
    const float* wk = (const float*)d_in[2];
    const float* wv = (const float*)d_in[3];
    const float* wo = (const float*)d_in[4];
    const float* qn = (const float*)d_in[5];
    const float* kn = (const float*)d_in[6];

    u16* ws = (u16*)d_ws;
    const size_t SZ_X = (size_t)BB * LL * DD;           // 8388608
    const size_t SZ_K = (size_t)BB * LL * KVH * HDIM;   // 4194304
    u16* xb  = ws;                    // SZ_X   (later reused as att)
    u16* q   = xb  + SZ_X;            // SZ_X
    u16* k   = q   + SZ_X;            // SZ_K
    u16* v   = k   + SZ_K;            // SZ_K
    u16* wqT = v   + SZ_K;            // DD*DD  (later reused as vt: B*KVH*HDIM*LL = DD*DD)
    u16* wkT = wqT + (size_t)DD * DD;
    u16* wvT = wkT + (size_t)DD * DD / 2;
    u16* woT = wvT + (size_t)DD * DD / 2;
    float* ct = (float*)(woT + (size_t)DD * DD);   // LL*64 floats
    float* st = ct + (size_t)LL * 64;
    u16* att = xb;
    u16* vt  = wqT;   // wqT dead after Q GEMM

    convert_f32_bf16<<<dim3((unsigned)(SZ_X / 1024)), dim3(256), 0, stream>>>(x, xb, (int)SZ_X);
    transpose_conv<<<dim3(32, 32), dim3(256), 0, stream>>>(wq, wqT, DD, DD);
    transpose_conv<<<dim3(16, 32), dim3(256), 0, stream>>>(wk, wkT, DD, KVH * HDIM);
    transpose_conv<<<dim3(16, 32), dim3(256), 0, stream>>>(wv, wvT, DD, KVH * HDIM);
    transpose_conv<<<dim3(32, 32), dim3(256), 0, stream>>>(wo, woT, HH * HDIM, DD);
    rope_table<<<dim3(LL * 64 / 256), dim3(256), 0, stream>>>(ct, st);

    gemm_bt<false><<<dim3(DD / 128, BB * LL / 128), dim3(256), 0, stream>>>(xb, wqT, q, BB * LL, DD, DD);
    gemm_bt<false><<<dim3(KVH * HDIM / 128, BB * LL / 128), dim3(256), 0, stream>>>(xb, wkT, k, BB * LL, KVH * HDIM, DD);
    gemm_bt<false><<<dim3(KVH * HDIM / 128, BB * LL / 128), dim3(256), 0, stream>>>(xb, wvT, v, BB * LL, KVH * HDIM, DD);

    rope_norm<<<dim3(BB * LL * (HH + KVH) / 4), dim3(256), 0, stream>>>(q, k, qn, kn, ct, st);
    transpose_v<<<dim3(LL / 64, HDIM / 64, BB * KVH), dim3(256), 0, stream>>>(v, vt);

    attn_kernel<<<dim3(LL / 64, BB * HH), dim3(256), 0, stream>>>(q, k, vt, att);
    gemm_bt<true><<<dim3(DD / 128, BB * LL / 128), dim3(256), 0, stream>>>(att, woT, d_out, BB * LL, DD, DD);
}

// Round 3
// 458.361 us; speedup vs baseline: 1.3797x; 1.1112x over previous
//
#include <hip/hip_runtime.h>
#include <math.h>

// Problem constants
#define BB 2
#define LL 2048
#define DD 2048
#define HH 16
#define KVH 8
#define HDIM 128
#define SCALE_F 0.08838834764831845f   // 128^-0.5
#define EPS_F 1e-5f
#define LOG2E 1.4426950408889634f
#define SMAX_F 17.0f                    // fixed softmax max (log2 domain); |s*SC2| <= 16.5

typedef unsigned short u16;
typedef __attribute__((ext_vector_type(8))) short short8;
typedef __attribute__((ext_vector_type(4))) float f32x4;

#define MFMA16(a, b, c) __builtin_amdgcn_mfma_f32_16x16x32_bf16((a), (b), (c), 0, 0, 0)

__device__ __forceinline__ float b2f(u16 u) {
    union { unsigned int i; float f; } x;
    x.i = ((unsigned int)u) << 16;
    return x.f;
}
__device__ __forceinline__ u16 f2b(float f) {
    unsigned int x = __float_as_uint(f);
    unsigned int r = x + 0x7FFFu + ((x >> 16) & 1u);   // round-to-nearest-even
    return (u16)(r >> 16);
}
__device__ __forceinline__ u16 f2b_fast(float f) {     // round-half-up, 2 VALU
    return (u16)((__float_as_uint(f) + 0x8000u) >> 16);
}
// async global->LDS, 16B per lane; LDS dest = base + lane*16 (HW-fixed)
__device__ __forceinline__ void g2l(const u16* g, u16* l) {
    __builtin_amdgcn_global_load_lds(
        (const __attribute__((address_space(1))) unsigned int*)g,
        (__attribute__((address_space(3))) unsigned int*)l, 16, 0, 0);
}

// ---------------------------------------------------------------------------
// fp32 -> bf16 convert (for x)
// ---------------------------------------------------------------------------
__global__ __launch_bounds__(256) void convert_f32_bf16(const float* __restrict__ in,
                                                        u16* __restrict__ out, int n) {
    int i = (blockIdx.x * 256 + threadIdx.x) * 4;
    if (i >= n) return;
    float4 v = *(const float4*)(in + i);
    unsigned int p0 = (unsigned int)f2b(v.x) | ((unsigned int)f2b(v.y) << 16);
    unsigned int p1 = (unsigned int)f2b(v.z) | ((unsigned int)f2b(v.w) << 16);
    uint2 pk; pk.x = p0; pk.y = p1;
    *(uint2*)(out + i) = pk;
}

// ---------------------------------------------------------------------------
// fp32 [R][C] -> bf16 transposed [C][R]
// ---------------------------------------------------------------------------
__global__ __launch_bounds__(256) void transpose_conv(const float* __restrict__ in,
                                                      u16* __restrict__ out, int R, int C) {
    __shared__ u16 t[64 * 65];
    int c0 = blockIdx.x * 64, r0 = blockIdx.y * 64;
#pragma unroll
    for (int i = 0; i < 16; i++) {
        int idx = threadIdx.x + i * 256;
        int r = idx >> 6, c = idx & 63;
        t[r * 65 + c] = f2b(in[(size_t)(r0 + r) * C + c0 + c]);
    }
    __syncthreads();
#pragma unroll
    for (int i = 0; i < 16; i++) {
        int idx = threadIdx.x + i * 256;
        int r = idx >> 6, c = idx & 63;
        out[(size_t)(c0 + r) * R + r0 + c] = t[c * 65 + r];
    }
}

// ---------------------------------------------------------------------------
// bf16 V [b][l][g][d] -> vt [b*8+g][d][l]
// ---------------------------------------------------------------------------
__global__ __launch_bounds__(256) void transpose_v(const u16* __restrict__ v,
                                                   u16* __restrict__ vt) {
    __shared__ u16 t[64 * 65];
    int l0 = blockIdx.x * 64, d0 = blockIdx.y * 64;
    int bg = blockIdx.z, b = bg >> 3, g = bg & 7;
    const u16* src = v + (size_t)b * LL * (KVH * HDIM) + g * HDIM;
    u16* dst = vt + (size_t)bg * HDIM * LL;
#pragma unroll
    for (int i = 0; i < 16; i++) {
        int idx = threadIdx.x + i * 256;
        int r = idx >> 6, c = idx & 63;
        t[r * 65 + c] = src[(size_t)(l0 + r) * (KVH * HDIM) + d0 + c];
    }
    __syncthreads();
#pragma unroll
    for (int i = 0; i < 16; i++) {
        int idx = threadIdx.x + i * 256;
        int r = idx >> 6, c = idx & 63;   // r = dim, c = key
        dst[(size_t)(d0 + r) * LL + l0 + c] = t[c * 65 + r];
    }
}

// ---------------------------------------------------------------------------
// RoPE cos/sin tables (numpy fp32 semantics)
// ---------------------------------------------------------------------------
__global__ __launch_bounds__(256) void rope_table(float* __restrict__ ct, float* __restrict__ st) {
    int i = blockIdx.x * 256 + threadIdx.x;   // i < LL*64
    int pos = i >> 6, d = i & 63;
    float freq = (float)pow(10000.0, (double)d * (1.0 / 64.0));
    float ang = (float)pos * freq;
    double a = (double)ang;
    ct[i] = (float)cos(a);
    st[i] = (float)sin(a);
}

// ---------------------------------------------------------------------------
// GEMM: C[M,N] = A[M,K] @ Bt[N,K]^T, m97 structure: global_load_lds width=16,
// unpadded 32-elem rows (conflict-free at 64B row stride), 128x128 tile.
// ---------------------------------------------------------------------------
template <bool F32OUT>
__global__ __launch_bounds__(256) void gemm_bt(const u16* __restrict__ A,
                                               const u16* __restrict__ Bt,
                                               void* __restrict__ Cv, int M, int N, int K) {
    __shared__ __align__(16) u16 As[128 * 32];
    __shared__ __align__(16) u16 Bs[128 * 32];
    const int tid = threadIdx.x;
    const int w = tid >> 6, lane = tid & 63;
    const int lm = lane & 15, lq = lane >> 4;
    const int bn0 = blockIdx.x * 128, bm0 = blockIdx.y * 128;
    const int wm = (w >> 1) * 64, wn = (w & 1) * 64;

    f32x4 acc[4][4];
#pragma unroll
    for (int i = 0; i < 4; i++)
#pragma unroll
        for (int j = 0; j < 4; j++) acc[i][j] = (f32x4){0.f, 0.f, 0.f, 0.f};

    const int sr = w * 32 + (lane >> 2);
    const int scc = lane & 3;
    const u16* ga = A + (size_t)(bm0 + sr) * K + scc * 8;
    const u16* gb = Bt + (size_t)(bn0 + sr) * K + scc * 8;
    u16* lA = &As[w * 1024];
    u16* lB = &Bs[w * 1024];

    for (int k0 = 0; k0 < K; k0 += 32) {
        __syncthreads();
        g2l(ga + k0, lA);
        g2l(ga + (size_t)16 * K + k0, lA + 512);
        g2l(gb + k0, lB);
        g2l(gb + (size_t)16 * K + k0, lB + 512);
        __syncthreads();

        short8 af[4], bf[4];
#pragma unroll
        for (int mt = 0; mt < 4; mt++)
            af[mt] = *(const short8*)(&As[(wm + mt * 16 + lm) * 32 + lq * 8]);
#pragma unroll
        for (int nt = 0; nt < 4; nt++)
            bf[nt] = *(const short8*)(&Bs[(wn + nt * 16 + lm) * 32 + lq * 8]);
#pragma unroll
        for (int mt = 0; mt < 4; mt++)
#pragma unroll
            for (int nt = 0; nt < 4; nt++) acc[mt][nt] = MFMA16(af[mt], bf[nt], acc[mt][nt]);
    }

#pragma unroll
    for (int mt = 0; mt < 4; mt++)
#pragma unroll
        for (int nt = 0; nt < 4; nt++)
#pragma unroll
            for (int r = 0; r < 4; r++) {
                int row = bm0 + wm + mt * 16 + lq * 4 + r;
                int col = bn0 + wn + nt * 16 + lm;
                if (F32OUT)
                    ((float*)Cv)[(size_t)row * N + col] = acc[mt][nt][r];
                else
                    ((u16*)Cv)[(size_t)row * N + col] = f2b(acc[mt][nt][r]);
            }
}

// ---------------------------------------------------------------------------
// Fused RoPE + RMSNorm, in-place on q and k. One wave per (row, head-slot).
// ---------------------------------------------------------------------------
__global__ __launch_bounds__(256) void rope_norm(u16* __restrict__ q, u16* __restrict__ k,
                                                 const float* __restrict__ qw,
                                                 const float* __restrict__ kw,
                                                 const float* __restrict__ ct,
                                                 const float* __restrict__ st) {
    int slot = blockIdx.x * 4 + (threadIdx.x >> 6);
    int lane = threadIdx.x & 63;
    int hh = slot % (HH + KVH);
    int row = slot / (HH + KVH);   // [0, B*L)
    int pos = row & (LL - 1);

    u16* base;
    const float* w;
    if (hh < HH) { base = q + (size_t)row * (HH * HDIM) + hh * HDIM; w = qw; }
    else         { base = k + (size_t)row * (KVH * HDIM) + (hh - HH) * HDIM; w = kw; }

    float x1 = b2f(base[lane]), x2 = b2f(base[lane + 64]);
    float c = ct[pos * 64 + lane], s = st[pos * 64 + lane];
    float r1 = x1 * c - x2 * s;
    float r2 = x2 * c + x1 * s;
    float ss = r1 * r1 + r2 * r2;
#pragma unroll
    for (int m = 1; m < 64; m <<= 1) ss += __shfl_xor(ss, m, 64);
    float sc = 1.0f / sqrtf(ss * (1.0f / 128.0f) + EPS_F);
    base[lane] = f2b(r1 * sc * w[lane]);
    base[lane + 64] = f2b(r2 * sc * w[lane + 64]);
}

// ---------------------------------------------------------------------------
// Flash attention, fixed-max softmax (no online rescale — scores provably
// bounded: |s*scale*log2e| <= 16.5 after RMSNorm, so p = exp2(s' - 17)).
// Block = 256 threads (4 waves) = 64 q-rows. 64-key tiles; K [key][dim] and
// V^T [dim][key] co-staged via global_load_lds w/ XOR granule swizzle
// (2 barriers/tile). Row sums deferred to one shuffle-reduce after the loop.
// LDS = 16K + 16K + 8K = 40960 B exactly -> 4 blocks/CU, zero tail.
// ---------------------------------------------------------------------------
__global__ __launch_bounds__(256, 4) void attn_kernel(const u16* __restrict__ qb,
                                                      const u16* __restrict__ kb,
                                                      const u16* __restrict__ vt,
                                                      u16* __restrict__ ob) {
    __shared__ __align__(16) u16 Kt[64 * 128];   // K tile [key][dim], 16 granules/row
    __shared__ __align__(16) u16 Vt[128 * 64];   // V^T tile [dim][key], 8 granules/row
    __shared__ __align__(16) u16 Ps[64 * 64];    // P staging, XOR-swizzled keys

    const int tid = threadIdx.x, w = tid >> 6, lane = tid & 63;
    const int lm = lane & 15, lq = lane >> 4;
    const int q0 = blockIdx.x * 64;
    const int bh = blockIdx.y, b = bh >> 4, hd = bh & 15, g = hd >> 1;

    const u16* kbase = kb + (size_t)b * LL * (KVH * HDIM) + g * HDIM;
    const u16* vtbase = vt + (size_t)(b * KVH + g) * HDIM * LL;

    // K staging: lane -> (row lane>>4, granule lane&15); 4 chunks of 4 rows/wave
    const int krl = lane >> 4, kgl = lane & 15;
    // V staging: lane -> (row lane>>3, granule lane&7); 4 chunks of 8 rows/wave
    const int vrl = lane >> 3, vgl = lane & 7;

    // Q fragments (A-layout: A[m=lm][k=lq*8+j])
    short8 aq[4];
    {
        size_t qoff = (size_t)(b * LL + q0 + w * 16 + lm) * (HH * HDIM) + hd * HDIM + lq * 8;
#pragma unroll
        for (int kk = 0; kk < 4; kk++) aq[kk] = *(const short8*)(qb + qoff + kk * 32);
    }

    f32x4 o[8];
#pragma unroll
    for (int i = 0; i < 8; i++) o[i] = (f32x4){0.f, 0.f, 0.f, 0.f};
    float psum[4] = {0.f, 0.f, 0.f, 0.f};
    const float SC2 = SCALE_F * LOG2E;

    for (int t = 0; t < LL / 64; t++) {
        __syncthreads();   // prior tile's fragment reads done before restaging
        // stage K tile [64 keys][128 dims], granule ^= (row & 15)
#pragma unroll
        for (int ch = 0; ch < 4; ch++) {
            int r = w * 16 + ch * 4 + krl;
            int gc = kgl ^ (r & 15);
            g2l(kbase + (size_t)(t * 64 + r) * (KVH * HDIM) + gc * 8,
                &Kt[(w * 16 + ch * 4) * 128]);
        }
        // stage V^T tile [128 dims][64 keys], granule ^= (row & 7)
#pragma unroll
        for (int ch = 0; ch < 4; ch++) {
            int r = w * 32 + ch * 8 + vrl;
            int gc = vgl ^ (r & 7);
            g2l(vtbase + (size_t)r * LL + t * 64 + gc * 8,
                &Vt[(w * 32 + ch * 8) * 64]);
        }
        __syncthreads();

        // S = Q @ K^T  (4 n-tiles of 16 keys)
        f32x4 s[4];
#pragma unroll
        for (int nt = 0; nt < 4; nt++) {
            s[nt] = (f32x4){0.f, 0.f, 0.f, 0.f};
#pragma unroll
            for (int kk = 0; kk < 4; kk++) {
                int gg = (kk * 4 + lq) ^ lm;
                short8 bf = *(const short8*)(&Kt[(nt * 16 + lm) * 128 + gg * 8]);
                s[nt] = MFMA16(aq[kk], bf, s[nt]);
            }
        }

        // P = exp2(s*SC2 - 17); accumulate lane-partial row sums; stage to LDS
#pragma unroll
        for (int nt = 0; nt < 4; nt++)
#pragma unroll
            for (int r = 0; r < 4; r++) {
                float p = exp2f(fmaf(s[nt][r], SC2, -SMAX_F));
                psum[r] += p;
                int row = lq * 4 + r;
                int keyx = (nt * 16 + lm) ^ ((row & 7) << 3);
                Ps[(w * 16 + row) * 64 + keyx] = f2b_fast(p);
            }

        // O += P @ V  (Ps is wave-private; compiler inserts the lgkm wait)
#pragma unroll
        for (int kk = 0; kk < 2; kk++) {
            int keyb = (kk * 32 + lq * 8) ^ ((lm & 7) << 3);
            short8 pa = *(const short8*)(&Ps[(w * 16 + lm) * 64 + keyb]);
#pragma unroll
            for (int dn = 0; dn < 8; dn++) {
                int gg = (kk * 4 + lq) ^ (lm & 7);
                short8 bv = *(const short8*)(&Vt[(dn * 16 + lm) * 64 + gg * 8]);
                o[dn] = MFMA16(pa, bv, o[dn]);
            }
        }
    }

    // deferred row-sum reduce over the 16 key-columns (lm lanes)
#pragma unroll
    for (int m = 1; m < 16; m <<= 1)
#pragma unroll
        for (int r = 0; r < 4; r++) psum[r] += __shfl_xor(psum[r], m, 64);
    float inv[4];
#pragma unroll
    for (int r = 0; r < 4; r++) inv[r] = 1.0f / psum[r];

    size_t obase = (size_t)(b * LL + q0 + w * 16 + lq * 4) * (HH * HDIM) + hd * HDIM;
#pragma unroll
    for (int dn = 0; dn < 8; dn++)
#pragma unroll
        for (int r = 0; r < 4; r++)
            ob[obase + (size_t)r * (HH * HDIM) + dn * 16 + lm] = f2b(o[dn][r] * inv[r]);
}

// ---------------------------------------------------------------------------
extern "C" void kernel_launch(void* const* d_in, const int* in_sizes, int n_in,
                              void* d_out, int out_size, void* d_ws, size_t ws_size,
                              hipStream_t stream) {
    const float* x  = (const float*)d_in[0];
    const float* wq = (const float*)d_in[1];
    const float* wk = (const float*)d_in[2];
    const float* wv = (const float*)d_in[3];
    const float* wo = (const float*)d_in[4];
    const float* qn = (const float*)d_in[5];
    const float* kn = (const float*)d_in[6];

    u16* ws = (u16*)d_ws;
    const size_t SZ_X = (size_t)BB * LL * DD;           // 8388608
    const size_t SZ_K = (size_t)BB * LL * KVH * HDIM;   // 4194304
    u16* xb  = ws;                    // SZ_X   (later reused as att)
    u16* q   = xb  + SZ_X;            // SZ_X
    u16* k   = q   + SZ_X;            // SZ_K
    u16* v   = k   + SZ_K;            // SZ_K
    u16* wqT = v   + SZ_K;            // DD*DD  (later reused as vt)
    u16* wkT = wqT + (size_t)DD * DD;
    u16* wvT = wkT + (size_t)DD * DD / 2;
    u16* woT = wvT + (size_t)DD * DD / 2;
    float* ct = (float*)(woT + (size_t)DD * DD);   // LL*64 floats
    float* st = ct + (size_t)LL * 64;
    u16* att = xb;
    u16* vt  = wqT;   // wqT dead after Q GEMM

    convert_f32_bf16<<<dim3((unsigned)(SZ_X / 1024)), dim3(256), 0, stream>>>(x, xb, (int)SZ_X);
    transpose_conv<<<dim3(32, 32), dim3(256), 0, stream>>>(wq, wqT, DD, DD);
    transpose_conv<<<dim3(16, 32), dim3(256), 0, stream>>>(wk, wkT, DD, KVH * HDIM);
    transpose_conv<<<dim3(16, 32), dim3(256), 0, stream>>>(wv, wvT, DD, KVH * HDIM);
    transpose_conv<<<dim3(32, 32), dim3(256), 0, stream>>>(wo, woT, HH * HDIM, DD);
    rope_table<<<dim3(LL * 64 / 256), dim3(256), 0, stream>>>(ct, st);

    gemm_bt<false><<<dim3(DD / 128, BB * LL / 128), dim3(256), 0, stream>>>(xb, wqT, q, BB * LL, DD, DD);
    gemm_bt<false><<<dim3(KVH * HDIM / 128, BB * LL / 128), dim3(256), 0, stream>>>(xb, wkT, k, BB * LL, KVH * HDIM, DD);
    gemm_bt<false><<<dim3(KVH * HDIM / 128, BB * LL / 128), dim3(256), 0, stream>>>(xb, wvT, v, BB * LL, KVH * HDIM, DD);

    rope_norm<<<dim3(BB * LL * (HH + KVH) / 4), dim3(256), 0, stream>>>(q, k, qn, kn, ct, st);
    transpose_v<<<dim3(LL / 64, HDIM / 64, BB * KVH), dim3(256), 0, stream>>>(v, vt);

    attn_kernel<<<dim3(LL / 64, BB * HH), dim3(256), 0, stream>>>(q, k, vt, att);
    gemm_bt<true><<<dim3(DD / 128, BB * LL / 128), dim3(256), 0, stream>>>(att, woT, d_out, BB * LL, DD, DD);
}

// Round 5
// 414.739 us; speedup vs baseline: 1.5248x; 1.1052x over previous
//
#include <hip/hip_runtime.h>
#include <math.h>

// Problem constants
#define BB 2
#define LL 2048
#define DD 2048
#define HH 16
#define KVH 8
#define HDIM 128
#define SCALE_F 0.08838834764831845f   // 128^-0.5
#define EPS_F 1e-5f
#define LOG2E 1.4426950408889634f
#define SMAX_F 17.0f                    // fixed softmax max (log2 domain); |s*SC2| <= 16.5
#define QKVW 4096                       // fused qkv row width: 16q + 8k + 8v heads

typedef unsigned short u16;
typedef __attribute__((ext_vector_type(8))) short short8;
typedef __attribute__((ext_vector_type(4))) float f32x4;

#define MFMA16(a, b, c) __builtin_amdgcn_mfma_f32_16x16x32_bf16((a), (b), (c), 0, 0, 0)

__device__ __forceinline__ float b2f(u16 u) {
    union { unsigned int i; float f; } x;
    x.i = ((unsigned int)u) << 16;
    return x.f;
}
__device__ __forceinline__ u16 f2b(float f) {
    unsigned int x = __float_as_uint(f);
    unsigned int r = x + 0x7FFFu + ((x >> 16) & 1u);   // round-to-nearest-even
    return (u16)(r >> 16);
}
__device__ __forceinline__ u16 f2b_fast(float f) {     // round-half-up, 2 VALU
    return (u16)((__float_as_uint(f) + 0x8000u) >> 16);
}
// async global->LDS, 16B per lane; LDS dest = base + lane*16 (HW-fixed)
__device__ __forceinline__ void g2l(const u16* g, u16* l) {
    __builtin_amdgcn_global_load_lds(
        (const __attribute__((address_space(1))) unsigned int*)g,
        (__attribute__((address_space(3))) unsigned int*)l, 16, 0, 0);
}

// ---------------------------------------------------------------------------
// fp32 -> bf16 convert (for x)
// ---------------------------------------------------------------------------
__global__ __launch_bounds__(256) void convert_f32_bf16(const float* __restrict__ in,
                                                        u16* __restrict__ out, int n) {
    int i = (blockIdx.x * 256 + threadIdx.x) * 4;
    if (i >= n) return;
    float4 v = *(const float4*)(in + i);
    unsigned int p0 = (unsigned int)f2b(v.x) | ((unsigned int)f2b(v.y) << 16);
    unsigned int p1 = (unsigned int)f2b(v.z) | ((unsigned int)f2b(v.w) << 16);
    uint2 pk; pk.x = p0; pk.y = p1;
    *(uint2*)(out + i) = pk;
}

// ---------------------------------------------------------------------------
// fp32 [R][C] -> bf16 transposed [C][R] (out row stride = R)
// ---------------------------------------------------------------------------
__global__ __launch_bounds__(256) void transpose_conv(const float* __restrict__ in,
                                                      u16* __restrict__ out, int R, int C) {
    __shared__ u16 t[64 * 65];
    int c0 = blockIdx.x * 64, r0 = blockIdx.y * 64;
#pragma unroll
    for (int i = 0; i < 16; i++) {
        int idx = threadIdx.x + i * 256;
        int r = idx >> 6, c = idx & 63;
        t[r * 65 + c] = f2b(in[(size_t)(r0 + r) * C + c0 + c]);
    }
    __syncthreads();
#pragma unroll
    for (int i = 0; i < 16; i++) {
        int idx = threadIdx.x + i * 256;
        int r = idx >> 6, c = idx & 63;
        out[(size_t)(c0 + r) * R + r0 + c] = t[c * 65 + r];
    }
}

// ---------------------------------------------------------------------------
// bf16 V columns of qkv [row][4096] (cols 3072 + g*128 + d) -> vt [b*8+g][d][l]
// ---------------------------------------------------------------------------
__global__ __launch_bounds__(256) void transpose_v(const u16* __restrict__ qkv,
                                                   u16* __restrict__ vt) {
    __shared__ u16 t[64 * 65];
    int l0 = blockIdx.x * 64, d0 = blockIdx.y * 64;
    int bg = blockIdx.z, b = bg >> 3, g = bg & 7;
    const u16* src = qkv + (size_t)b * LL * QKVW + 3072 + g * HDIM;
    u16* dst = vt + (size_t)bg * HDIM * LL;
#pragma unroll
    for (int i = 0; i < 16; i++) {
        int idx = threadIdx.x + i * 256;
        int r = idx >> 6, c = idx & 63;
        t[r * 65 + c] = src[(size_t)(l0 + r) * QKVW + d0 + c];
    }
    __syncthreads();
#pragma unroll
    for (int i = 0; i < 16; i++) {
        int idx = threadIdx.x + i * 256;
        int r = idx >> 6, c = idx & 63;   // r = dim, c = key
        dst[(size_t)(d0 + r) * LL + l0 + c] = t[c * 65 + r];
    }
}

// ---------------------------------------------------------------------------
// RoPE cos/sin tables (numpy fp32 semantics)
// ---------------------------------------------------------------------------
__global__ __launch_bounds__(256) void rope_table(float* __restrict__ ct, float* __restrict__ st) {
    int i = blockIdx.x * 256 + threadIdx.x;   // i < LL*64
    int pos = i >> 6, d = i & 63;
    float freq = (float)pow(10000.0, (double)d * (1.0 / 64.0));
    float ang = (float)pos * freq;
    double a = (double)ang;
    ct[i] = (float)cos(a);
    st[i] = (float)sin(a);
}

// ---------------------------------------------------------------------------
// GEMM: C[M,N] = A[M,K] @ Bt[N,K]^T, m97 structure: global_load_lds width=16,
// unpadded 32-elem rows (conflict-free at 64B row stride), 128x128 tile.
// ---------------------------------------------------------------------------
template <bool F32OUT>
__global__ __launch_bounds__(256) void gemm_bt(const u16* __restrict__ A,
                                               const u16* __restrict__ Bt,
                                               void* __restrict__ Cv, int M, int N, int K) {
    __shared__ __align__(16) u16 As[128 * 32];
    __shared__ __align__(16) u16 Bs[128 * 32];
    const int tid = threadIdx.x;
    const int w = tid >> 6, lane = tid & 63;
    const int lm = lane & 15, lq = lane >> 4;
    const int bn0 = blockIdx.x * 128, bm0 = blockIdx.y * 128;
    const int wm = (w >> 1) * 64, wn = (w & 1) * 64;

    f32x4 acc[4][4];
#pragma unroll
    for (int i = 0; i < 4; i++)
#pragma unroll
        for (int j = 0; j < 4; j++) acc[i][j] = (f32x4){0.f, 0.f, 0.f, 0.f};

    const int sr = w * 32 + (lane >> 2);
    const int scc = lane & 3;
    const u16* ga = A + (size_t)(bm0 + sr) * K + scc * 8;
    const u16* gb = Bt + (size_t)(bn0 + sr) * K + scc * 8;
    u16* lA = &As[w * 1024];
    u16* lB = &Bs[w * 1024];

    for (int k0 = 0; k0 < K; k0 += 32) {
        __syncthreads();
        g2l(ga + k0, lA);
        g2l(ga + (size_t)16 * K + k0, lA + 512);
        g2l(gb + k0, lB);
        g2l(gb + (size_t)16 * K + k0, lB + 512);
        __syncthreads();

        short8 af[4], bf[4];
#pragma unroll
        for (int mt = 0; mt < 4; mt++)
            af[mt] = *(const short8*)(&As[(wm + mt * 16 + lm) * 32 + lq * 8]);
#pragma unroll
        for (int nt = 0; nt < 4; nt++)
            bf[nt] = *(const short8*)(&Bs[(wn + nt * 16 + lm) * 32 + lq * 8]);
#pragma unroll
        for (int mt = 0; mt < 4; mt++)
#pragma unroll
            for (int nt = 0; nt < 4; nt++) acc[mt][nt] = MFMA16(af[mt], bf[nt], acc[mt][nt]);
    }

#pragma unroll
    for (int mt = 0; mt < 4; mt++)
#pragma unroll
        for (int nt = 0; nt < 4; nt++)
#pragma unroll
            for (int r = 0; r < 4; r++) {
                int row = bm0 + wm + mt * 16 + lq * 4 + r;
                int col = bn0 + wn + nt * 16 + lm;
                if (F32OUT)
                    ((float*)Cv)[(size_t)row * N + col] = acc[mt][nt][r];
                else
                    ((u16*)Cv)[(size_t)row * N + col] = f2b(acc[mt][nt][r]);
            }
}

// ---------------------------------------------------------------------------
// Fused RoPE + RMSNorm, in-place on qkv (slots 0..15 = q heads, 16..23 = k heads;
// col = slot*128 in the fused row). One wave per (row, slot).
// ---------------------------------------------------------------------------
__global__ __launch_bounds__(256) void rope_norm(u16* __restrict__ qkv,
                                                 const float* __restrict__ qw,
                                                 const float* __restrict__ kw,
                                                 const float* __restrict__ ct,
                                                 const float* __restrict__ st) {
    int slot = blockIdx.x * 4 + (threadIdx.x >> 6);
    int lane = threadIdx.x & 63;
    int hh = slot % (HH + KVH);
    int row = slot / (HH + KVH);   // [0, B*L)
    int pos = row & (LL - 1);

    u16* base = qkv + (size_t)row * QKVW + hh * HDIM;
    const float* w = (hh < HH) ? qw : kw;

    float x1 = b2f(base[lane]), x2 = b2f(base[lane + 64]);
    float c = ct[pos * 64 + lane], s = st[pos * 64 + lane];
    float r1 = x1 * c - x2 * s;
    float r2 = x2 * c + x1 * s;
    float ss = r1 * r1 + r2 * r2;
#pragma unroll
    for (int m = 1; m < 64; m <<= 1) ss += __shfl_xor(ss, m, 64);
    float sc = 1.0f / sqrtf(ss * (1.0f / 128.0f) + EPS_F);
    base[lane] = f2b(r1 * sc * w[lane]);
    base[lane + 64] = f2b(r2 * sc * w[lane + 64]);
}

// ---------------------------------------------------------------------------
// Flash attention — ROUND-3-VERIFIED kernel (16x16x32 MFMA, fixed-max softmax),
// adapted only for the fused qkv layout (q cols hd*128, k cols 2048+g*128,
// row stride QKVW; single qkv pointer so no restrict aliasing).
// Block = 256 threads (4 waves) = 64 q-rows. 64-key tiles; K [key][dim] and
// V^T [dim][key] co-staged via global_load_lds w/ XOR granule swizzle
// (2 barriers/tile). LDS = 40960 B -> 4 blocks/CU.
// ---------------------------------------------------------------------------
__global__ __launch_bounds__(256, 4) void attn_kernel(const u16* __restrict__ qkv,
                                                      const u16* __restrict__ vt,
                                                      u16* __restrict__ ob) {
    __shared__ __align__(16) u16 Kt[64 * 128];   // K tile [key][dim], 16 granules/row
    __shared__ __align__(16) u16 Vt[128 * 64];   // V^T tile [dim][key], 8 granules/row
    __shared__ __align__(16) u16 Ps[64 * 64];    // P staging, XOR-swizzled keys

    const int tid = threadIdx.x, w = tid >> 6, lane = tid & 63;
    const int lm = lane & 15, lq = lane >> 4;
    const int q0 = blockIdx.x * 64;
    const int bh = blockIdx.y, b = bh >> 4, hd = bh & 15, g = hd >> 1;

    const u16* kbase = qkv + (size_t)b * LL * QKVW + 2048 + g * HDIM;
    const u16* vtbase = vt + (size_t)(b * KVH + g) * HDIM * LL;

    // K staging: lane -> (row lane>>4, granule lane&15); 4 chunks of 4 rows/wave
    const int krl = lane >> 4, kgl = lane & 15;
    // V staging: lane -> (row lane>>3, granule lane&7); 4 chunks of 8 rows/wave
    const int vrl = lane >> 3, vgl = lane & 7;

    // Q fragments (A-layout: A[m=lm][k=lq*8+j])
    short8 aq[4];
    {
        size_t qoff = (size_t)(b * LL + q0 + w * 16 + lm) * QKVW + hd * HDIM + lq * 8;
#pragma unroll
        for (int kk = 0; kk < 4; kk++) aq[kk] = *(const short8*)(qkv + qoff + kk * 32);
    }

    f32x4 o[8];
#pragma unroll
    for (int i = 0; i < 8; i++) o[i] = (f32x4){0.f, 0.f, 0.f, 0.f};
    float psum[4] = {0.f, 0.f, 0.f, 0.f};
    const float SC2 = SCALE_F * LOG2E;

    for (int t = 0; t < LL / 64; t++) {
        __syncthreads();   // prior tile's fragment reads done before restaging
        // stage K tile [64 keys][128 dims], granule ^= (row & 15)
#pragma unroll
        for (int ch = 0; ch < 4; ch++) {
            int r = w * 16 + ch * 4 + krl;
            int gc = kgl ^ (r & 15);
            g2l(kbase + (size_t)(t * 64 + r) * QKVW + gc * 8,
                &Kt[(w * 16 + ch * 4) * 128]);
        }
        // stage V^T tile [128 dims][64 keys], granule ^= (row & 7)
#pragma unroll
        for (int ch = 0; ch < 4; ch++) {
            int r = w * 32 + ch * 8 + vrl;
            int gc = vgl ^ (r & 7);
            g2l(vtbase + (size_t)r * LL + t * 64 + gc * 8,
                &Vt[(w * 32 + ch * 8) * 64]);
        }
        __syncthreads();

        // S = Q @ K^T  (4 n-tiles of 16 keys)
        f32x4 s[4];
#pragma unroll
        for (int nt = 0; nt < 4; nt++) {
            s[nt] = (f32x4){0.f, 0.f, 0.f, 0.f};
#pragma unroll
            for (int kk = 0; kk < 4; kk++) {
                int gg = (kk * 4 + lq) ^ lm;
                short8 bf = *(const short8*)(&Kt[(nt * 16 + lm) * 128 + gg * 8]);
                s[nt] = MFMA16(aq[kk], bf, s[nt]);
            }
        }

        // P = exp2(s*SC2 - 17); accumulate lane-partial row sums; stage to LDS
#pragma unroll
        for (int nt = 0; nt < 4; nt++)
#pragma unroll
            for (int r = 0; r < 4; r++) {
                float p = exp2f(fmaf(s[nt][r], SC2, -SMAX_F));
                psum[r] += p;
                int row = lq * 4 + r;
                int keyx = (nt * 16 + lm) ^ ((row & 7) << 3);
                Ps[(w * 16 + row) * 64 + keyx] = f2b_fast(p);
            }

        // O += P @ V  (Ps is wave-private; compiler inserts the lgkm wait)
#pragma unroll
        for (int kk = 0; kk < 2; kk++) {
            int keyb = (kk * 32 + lq * 8) ^ ((lm & 7) << 3);
            short8 pa = *(const short8*)(&Ps[(w * 16 + lm) * 64 + keyb]);
#pragma unroll
            for (int dn = 0; dn < 8; dn++) {
                int gg = (kk * 4 + lq) ^ (lm & 7);
                short8 bv = *(const short8*)(&Vt[(dn * 16 + lm) * 64 + gg * 8]);
                o[dn] = MFMA16(pa, bv, o[dn]);
            }
        }
    }

    // deferred row-sum reduce over the 16 key-columns (lm lanes)
#pragma unroll
    for (int m = 1; m < 16; m <<= 1)
#pragma unroll
        for (int r = 0; r < 4; r++) psum[r] += __shfl_xor(psum[r], m, 64);
    float inv[4];
#pragma unroll
    for (int r = 0; r < 4; r++) inv[r] = 1.0f / psum[r];

    size_t obase = (size_t)(b * LL + q0 + w * 16 + lq * 4) * (HH * HDIM) + hd * HDIM;
#pragma unroll
    for (int dn = 0; dn < 8; dn++)
#pragma unroll
        for (int r = 0; r < 4; r++)
            ob[obase + (size_t)r * (HH * HDIM) + dn * 16 + lm] = f2b(o[dn][r] * inv[r]);
}

// ---------------------------------------------------------------------------
extern "C" void kernel_launch(void* const* d_in, const int* in_sizes, int n_in,
                              void* d_out, int out_size, void* d_ws, size_t ws_size,
                              hipStream_t stream) {
    const float* x  = (const float*)d_in[0];
    const float* wq = (const float*)d_in[1];
    const float* wk = (const float*)d_in[2];
    const float* wv = (const float*)d_in[3];
    const float* wo = (const float*)d_in[4];
    const float* qn = (const float*)d_in[5];
    const float* kn = (const float*)d_in[6];

    u16* ws = (u16*)d_ws;
    const size_t SZ_X = (size_t)BB * LL * DD;          // 8388608
    u16* xb    = ws;                         // SZ_X (later reused as att)
    u16* qkv   = xb + SZ_X;                  // B*L*4096 = 16.8M
    u16* wqkvT = qkv + (size_t)BB * LL * QKVW;  // 4096*2048 (later reused as vt)
    u16* woT   = wqkvT + (size_t)QKVW * DD;  // 2048*2048
    float* ct  = (float*)(woT + (size_t)DD * DD);   // LL*64 floats
    float* st  = ct + (size_t)LL * 64;
    u16* att = xb;
    u16* vt  = wqkvT;   // dead after fused QKV GEMM

    convert_f32_bf16<<<dim3((unsigned)(SZ_X / 1024)), dim3(256), 0, stream>>>(x, xb, (int)SZ_X);
    // fused transposed weights: rows 0..2047 = wq cols, 2048..3071 = wk, 3072..4095 = wv
    transpose_conv<<<dim3(32, 32), dim3(256), 0, stream>>>(wq, wqkvT, DD, DD);
    transpose_conv<<<dim3(16, 32), dim3(256), 0, stream>>>(wk, wqkvT + (size_t)2048 * DD, DD, KVH * HDIM);
    transpose_conv<<<dim3(16, 32), dim3(256), 0, stream>>>(wv, wqkvT + (size_t)3072 * DD, DD, KVH * HDIM);
    transpose_conv<<<dim3(32, 32), dim3(256), 0, stream>>>(wo, woT, HH * HDIM, DD);
    rope_table<<<dim3(LL * 64 / 256), dim3(256), 0, stream>>>(ct, st);

    // fused QKV projection: [B*L, 4096] = xb @ wqkvT^T
    gemm_bt<false><<<dim3(QKVW / 128, BB * LL / 128), dim3(256), 0, stream>>>(xb, wqkvT, qkv, BB * LL, QKVW, DD);

    rope_norm<<<dim3(BB * LL * (HH + KVH) / 4), dim3(256), 0, stream>>>(qkv, qn, kn, ct, st);
    transpose_v<<<dim3(LL / 64, HDIM / 64, BB * KVH), dim3(256), 0, stream>>>(qkv, vt);

    attn_kernel<<<dim3(LL / 64, BB * HH), dim3(256), 0, stream>>>(qkv, vt, att);
    gemm_bt<true><<<dim3(DD / 128, BB * LL / 128), dim3(256), 0, stream>>>(att, woT, d_out, BB * LL, DD, DD);
}

// Round 6
// 412.177 us; speedup vs baseline: 1.5343x; 1.0062x over previous
//
#include <hip/hip_runtime.h>
#include <math.h>

// Problem constants
#define BB 2
#define LL 2048
#define DD 2048
#define HH 16
#define KVH 8
#define HDIM 128
#define SCALE_F 0.08838834764831845f   // 128^-0.5
#define EPS_F 1e-5f
#define LOG2E 1.4426950408889634f
#define SMAX_F 17.0f                    // fixed softmax max (log2 domain); |s*SC2| <= 16.5
#define QKVW 4096                       // fused qkv row width: 16q + 8k + 8v heads

typedef unsigned short u16;
typedef __attribute__((ext_vector_type(8))) short short8;
typedef __attribute__((ext_vector_type(4))) float f32x4;
typedef __attribute__((ext_vector_type(16))) float f32x16;

#define MFMA16(a, b, c) __builtin_amdgcn_mfma_f32_16x16x32_bf16((a), (b), (c), 0, 0, 0)
#define MFMA32(a, b, c) __builtin_amdgcn_mfma_f32_32x32x16_bf16((a), (b), (c), 0, 0, 0)

__device__ __forceinline__ float b2f(u16 u) {
    union { unsigned int i; float f; } x;
    x.i = ((unsigned int)u) << 16;
    return x.f;
}
__device__ __forceinline__ u16 f2b(float f) {
    unsigned int x = __float_as_uint(f);
    unsigned int r = x + 0x7FFFu + ((x >> 16) & 1u);   // round-to-nearest-even
    return (u16)(r >> 16);
}
__device__ __forceinline__ u16 f2b_fast(float f) {     // round-half-up, 2 VALU
    return (u16)((__float_as_uint(f) + 0x8000u) >> 16);
}
// async global->LDS, 16B per lane; LDS dest = base + lane*16 (HW-fixed)
__device__ __forceinline__ void g2l(const u16* g, u16* l) {
    __builtin_amdgcn_global_load_lds(
        (const __attribute__((address_space(1))) unsigned int*)g,
        (__attribute__((address_space(3))) unsigned int*)l, 16, 0, 0);
}

// ---------------------------------------------------------------------------
// fp32 -> bf16 convert (for x)
// ---------------------------------------------------------------------------
__global__ __launch_bounds__(256) void convert_f32_bf16(const float* __restrict__ in,
                                                        u16* __restrict__ out, int n) {
    int i = (blockIdx.x * 256 + threadIdx.x) * 4;
    if (i >= n) return;
    float4 v = *(const float4*)(in + i);
    unsigned int p0 = (unsigned int)f2b(v.x) | ((unsigned int)f2b(v.y) << 16);
    unsigned int p1 = (unsigned int)f2b(v.z) | ((unsigned int)f2b(v.w) << 16);
    uint2 pk; pk.x = p0; pk.y = p1;
    *(uint2*)(out + i) = pk;
}

// ---------------------------------------------------------------------------
// fp32 [R][C] -> bf16 transposed [C][R] (out row stride = R)
// ---------------------------------------------------------------------------
__global__ __launch_bounds__(256) void transpose_conv(const float* __restrict__ in,
                                                      u16* __restrict__ out, int R, int C) {
    __shared__ u16 t[64 * 65];
    int c0 = blockIdx.x * 64, r0 = blockIdx.y * 64;
#pragma unroll
    for (int i = 0; i < 16; i++) {
        int idx = threadIdx.x + i * 256;
        int r = idx >> 6, c = idx & 63;
        t[r * 65 + c] = f2b(in[(size_t)(r0 + r) * C + c0 + c]);
    }
    __syncthreads();
#pragma unroll
    for (int i = 0; i < 16; i++) {
        int idx = threadIdx.x + i * 256;
        int r = idx >> 6, c = idx & 63;
        out[(size_t)(c0 + r) * R + r0 + c] = t[c * 65 + r];
    }
}

// ---------------------------------------------------------------------------
// bf16 V columns of qkv [row][4096] (cols 3072 + g*128 + d) -> vt [b*8+g][d][l]
// ---------------------------------------------------------------------------
__global__ __launch_bounds__(256) void transpose_v(const u16* __restrict__ qkv,
                                                   u16* __restrict__ vt) {
    __shared__ u16 t[64 * 65];
    int l0 = blockIdx.x * 64, d0 = blockIdx.y * 64;
    int bg = blockIdx.z, b = bg >> 3, g = bg & 7;
    const u16* src = qkv + (size_t)b * LL * QKVW + 3072 + g * HDIM;
    u16* dst = vt + (size_t)bg * HDIM * LL;
#pragma unroll
    for (int i = 0; i < 16; i++) {
        int idx = threadIdx.x + i * 256;
        int r = idx >> 6, c = idx & 63;
        t[r * 65 + c] = src[(size_t)(l0 + r) * QKVW + d0 + c];
    }
    __syncthreads();
#pragma unroll
    for (int i = 0; i < 16; i++) {
        int idx = threadIdx.x + i * 256;
        int r = idx >> 6, c = idx & 63;   // r = dim, c = key
        dst[(size_t)(d0 + r) * LL + l0 + c] = t[c * 65 + r];
    }
}

// ---------------------------------------------------------------------------
// RoPE cos/sin tables (numpy fp32 semantics)
// ---------------------------------------------------------------------------
__global__ __launch_bounds__(256) void rope_table(float* __restrict__ ct, float* __restrict__ st) {
    int i = blockIdx.x * 256 + threadIdx.x;   // i < LL*64
    int pos = i >> 6, d = i & 63;
    float freq = (float)pow(10000.0, (double)d * (1.0 / 64.0));
    float ang = (float)pos * freq;
    double a = (double)ang;
    ct[i] = (float)cos(a);
    st[i] = (float)sin(a);
}

// ---------------------------------------------------------------------------
// GEMM: C[M,N] = A[M,K] @ Bt[N,K]^T, m97 structure: global_load_lds width=16,
// unpadded 32-elem rows (conflict-free at 64B row stride), 128x128 tile.
// ---------------------------------------------------------------------------
template <bool F32OUT>
__global__ __launch_bounds__(256) void gemm_bt(const u16* __restrict__ A,
                                               const u16* __restrict__ Bt,
                                               void* __restrict__ Cv, int M, int N, int K) {
    __shared__ __align__(16) u16 As[128 * 32];
    __shared__ __align__(16) u16 Bs[128 * 32];
    const int tid = threadIdx.x;
    const int w = tid >> 6, lane = tid & 63;
    const int lm = lane & 15, lq = lane >> 4;
    const int bn0 = blockIdx.x * 128, bm0 = blockIdx.y * 128;
    const int wm = (w >> 1) * 64, wn = (w & 1) * 64;

    f32x4 acc[4][4];
#pragma unroll
    for (int i = 0; i < 4; i++)
#pragma unroll
        for (int j = 0; j < 4; j++) acc[i][j] = (f32x4){0.f, 0.f, 0.f, 0.f};

    const int sr = w * 32 + (lane >> 2);
    const int scc = lane & 3;
    const u16* ga = A + (size_t)(bm0 + sr) * K + scc * 8;
    const u16* gb = Bt + (size_t)(bn0 + sr) * K + scc * 8;
    u16* lA = &As[w * 1024];
    u16* lB = &Bs[w * 1024];

    for (int k0 = 0; k0 < K; k0 += 32) {
        __syncthreads();
        g2l(ga + k0, lA);
        g2l(ga + (size_t)16 * K + k0, lA + 512);
        g2l(gb + k0, lB);
        g2l(gb + (size_t)16 * K + k0, lB + 512);
        __syncthreads();

        short8 af[4], bf[4];
#pragma unroll
        for (int mt = 0; mt < 4; mt++)
            af[mt] = *(const short8*)(&As[(wm + mt * 16 + lm) * 32 + lq * 8]);
#pragma unroll
        for (int nt = 0; nt < 4; nt++)
            bf[nt] = *(const short8*)(&Bs[(wn + nt * 16 + lm) * 32 + lq * 8]);
#pragma unroll
        for (int mt = 0; mt < 4; mt++)
#pragma unroll
            for (int nt = 0; nt < 4; nt++) acc[mt][nt] = MFMA16(af[mt], bf[nt], acc[mt][nt]);
    }

#pragma unroll
    for (int mt = 0; mt < 4; mt++)
#pragma unroll
        for (int nt = 0; nt < 4; nt++)
#pragma unroll
            for (int r = 0; r < 4; r++) {
                int row = bm0 + wm + mt * 16 + lq * 4 + r;
                int col = bn0 + wn + nt * 16 + lm;
                if (F32OUT)
                    ((float*)Cv)[(size_t)row * N + col] = acc[mt][nt][r];
                else
                    ((u16*)Cv)[(size_t)row * N + col] = f2b(acc[mt][nt][r]);
            }
}

// ---------------------------------------------------------------------------
// Fused RoPE + RMSNorm, in-place on qkv (slots 0..15 = q heads, 16..23 = k heads;
// col = slot*128 in the fused row). One wave per (row, slot).
// ---------------------------------------------------------------------------
__global__ __launch_bounds__(256) void rope_norm(u16* __restrict__ qkv,
                                                 const float* __restrict__ qw,
                                                 const float* __restrict__ kw,
                                                 const float* __restrict__ ct,
                                                 const float* __restrict__ st) {
    int slot = blockIdx.x * 4 + (threadIdx.x >> 6);
    int lane = threadIdx.x & 63;
    int hh = slot % (HH + KVH);
    int row = slot / (HH + KVH);   // [0, B*L)
    int pos = row & (LL - 1);

    u16* base = qkv + (size_t)row * QKVW + hh * HDIM;
    const float* w = (hh < HH) ? qw : kw;

    float x1 = b2f(base[lane]), x2 = b2f(base[lane + 64]);
    float c = ct[pos * 64 + lane], s = st[pos * 64 + lane];
    float r1 = x1 * c - x2 * s;
    float r2 = x2 * c + x1 * s;
    float ss = r1 * r1 + r2 * r2;
#pragma unroll
    for (int m = 1; m < 64; m <<= 1) ss += __shfl_xor(ss, m, 64);
    float sc = 1.0f / sqrtf(ss * (1.0f / 128.0f) + EPS_F);
    base[lane] = f2b(r1 * sc * w[lane]);
    base[lane + 64] = f2b(r2 * sc * w[lane + 64]);
}

// ---------------------------------------------------------------------------
// Flash attention, 32x32x16 MFMA, fixed-max softmax. HARDENED re-land of the
// round-4 kernel: explicit __syncthreads() between P staging (ds_write_b16)
// and PV fragment reads (ds_read_b128) — no reliance on same-wave DS
// ordering surviving compiler scheduling. 3 barriers/tile total.
// Block = 256 threads (4 waves) = 128 q-rows (wave -> 32 rows). 64-key tiles.
// K [key][dim] 16KB + V^T [dim][key] 16KB via global_load_lds w/ XOR granule
// swizzle; per-wave P 16KB. LDS = 48KB. Grid 512 blocks = 2/CU.
// C-layout (m74/m101): col=lane&31, row=(reg&3)+8*(reg>>2)+4*(lane>>5).
// ---------------------------------------------------------------------------
__global__ __launch_bounds__(256, 2) void attn_kernel(const u16* __restrict__ qkv,
                                                      const u16* __restrict__ vt,
                                                      u16* __restrict__ ob) {
    __shared__ __align__(16) u16 Kt[64 * 128];   // [key][dim] 16 granules/row
    __shared__ __align__(16) u16 Vt[128 * 64];   // [dim][key] 8 granules/row
    __shared__ __align__(16) u16 Ps[4][32 * 64]; // per-wave P, key ^= (row&7)<<3

    const int tid = threadIdx.x, w = tid >> 6, lane = tid & 63;
    const int l31 = lane & 31, lh = lane >> 5;
    const int q0 = blockIdx.x * 128;
    const int bh = blockIdx.y, b = bh >> 4, hd = bh & 15, g = hd >> 1;

    const u16* kbase = qkv + (size_t)b * LL * QKVW + 2048 + g * HDIM;
    const u16* vtbase = vt + (size_t)(b * KVH + g) * HDIM * LL;

    // K staging: lane -> (row lane>>4, granule lane&15)
    const int krl = lane >> 4, kgl = lane & 15;
    // V staging: lane -> (row lane>>3, granule lane&7)
    const int vrl = lane >> 3, vgl = lane & 7;

    // Q fragments (A of 32x32x16: m=lane&31, k = kk*16 + lh*8 + j)
    const int qrow = q0 + w * 32 + l31;
    short8 aq[8];
    {
        const u16* qp = qkv + (size_t)(b * LL + qrow) * QKVW + hd * HDIM + lh * 8;
#pragma unroll
        for (int kk = 0; kk < 8; kk++) aq[kk] = *(const short8*)(qp + kk * 16);
    }

    f32x16 o[4];
#pragma unroll
    for (int i = 0; i < 4; i++)
#pragma unroll
        for (int r = 0; r < 16; r++) o[i][r] = 0.f;
    float psum[16];
#pragma unroll
    for (int r = 0; r < 16; r++) psum[r] = 0.f;
    const float SC2 = SCALE_F * LOG2E;

    for (int t = 0; t < LL / 64; t++) {
        __syncthreads();   // (a) prior tile's Kt/Vt fragment reads done
        // stage K tile [64 keys][128 dims], granule ^= (row & 15)
#pragma unroll
        for (int ch = 0; ch < 4; ch++) {
            int r = w * 16 + ch * 4 + krl;
            int gc = kgl ^ (r & 15);
            g2l(kbase + (size_t)(t * 64 + r) * QKVW + gc * 8,
                &Kt[(w * 16 + ch * 4) * 128]);
        }
        // stage V^T tile [128 dims][64 keys], granule ^= (row & 7)
#pragma unroll
        for (int ch = 0; ch < 4; ch++) {
            int r = w * 32 + ch * 8 + vrl;
            int gc = vgl ^ (r & 7);
            g2l(vtbase + (size_t)r * LL + t * 64 + gc * 8,
                &Vt[(w * 32 + ch * 8) * 64]);
        }
        __syncthreads();   // (b) staging complete

        // S = Q @ K^T  (2 key-tiles of 32)
        f32x16 s[2];
#pragma unroll
        for (int kt = 0; kt < 2; kt++) {
#pragma unroll
            for (int r = 0; r < 16; r++) s[kt][r] = 0.f;
            int key = kt * 32 + l31;
#pragma unroll
            for (int kk = 0; kk < 8; kk++) {
                int gg = (kk * 2 + lh) ^ (key & 15);
                short8 bf = *(const short8*)(&Kt[key * 128 + gg * 8]);
                s[kt] = MFMA32(aq[kk], bf, s[kt]);
            }
        }

        // P = exp2(s*SC2 - 17); lane-partial row sums; stage to per-wave Ps
#pragma unroll
        for (int kt = 0; kt < 2; kt++) {
            int key = kt * 32 + l31;
#pragma unroll
            for (int r = 0; r < 16; r++) {
                float p = exp2f(fmaf(s[kt][r], SC2, -SMAX_F));
                psum[r] += p;
                int row = (r & 3) + 8 * (r >> 2) + 4 * lh;
                Ps[w][row * 64 + (key ^ ((row & 7) << 3))] = f2b_fast(p);
            }
        }
        __syncthreads();   // (c) HARDENING: all P writes visible before b128 reads

        // O += P @ V  (A=P from Ps b128 reads, B=V^T b128 reads)
#pragma unroll
        for (int kc = 0; kc < 4; kc++) {
            int gp = ((kc * 2 + lh) ^ (l31 & 7)) * 8;
            short8 pa = *(const short8*)(&Ps[w][l31 * 64 + gp]);
#pragma unroll
            for (int dn = 0; dn < 4; dn++) {
                int d = dn * 32 + l31;
                int gv = ((kc * 2 + lh) ^ (d & 7)) * 8;
                short8 bv = *(const short8*)(&Vt[d * 64 + gv]);
                o[dn] = MFMA32(pa, bv, o[dn]);
            }
        }
    }

    // deferred row-sum reduce: psum[r] holds this lane's 2-key/tile partials;
    // total for row (r,lh) = sum over the 32 lanes sharing lh
#pragma unroll
    for (int m = 1; m < 32; m <<= 1)
#pragma unroll
        for (int r = 0; r < 16; r++) psum[r] += __shfl_xor(psum[r], m, 32);
    float inv[16];
#pragma unroll
    for (int r = 0; r < 16; r++) inv[r] = 1.0f / psum[r];

    // O: col = dim = dn*32 + l31, row = (r&3)+8*(r>>2)+4*lh
    u16* obase = ob + (size_t)(b * LL + q0 + w * 32) * (HH * HDIM) + hd * HDIM;
#pragma unroll
    for (int dn = 0; dn < 4; dn++)
#pragma unroll
        for (int r = 0; r < 16; r++) {
            int row = (r & 3) + 8 * (r >> 2) + 4 * lh;
            obase[(size_t)row * (HH * HDIM) + dn * 32 + l31] = f2b(o[dn][r] * inv[r]);
        }
}

// ---------------------------------------------------------------------------
extern "C" void kernel_launch(void* const* d_in, const int* in_sizes, int n_in,
                              void* d_out, int out_size, void* d_ws, size_t ws_size,
                              hipStream_t stream) {
    const float* x  = (const float*)d_in[0];
    const float* wq = (const float*)d_in[1];
    const float* wk = (const float*)d_in[2];
    const float* wv = (const float*)d_in[3];
    const float* wo = (const float*)d_in[4];
    const float* qn = (const float*)d_in[5];
    const float* kn = (const float*)d_in[6];

    u16* ws = (u16*)d_ws;
    const size_t SZ_X = (size_t)BB * LL * DD;          // 8388608
    u16* xb    = ws;                         // SZ_X (later reused as att)
    u16* qkv   = xb + SZ_X;                  // B*L*4096 = 16.8M
    u16* wqkvT = qkv + (size_t)BB * LL * QKVW;  // 4096*2048 (later reused as vt)
    u16* woT   = wqkvT + (size_t)QKVW * DD;  // 2048*2048
    float* ct  = (float*)(woT + (size_t)DD * DD);   // LL*64 floats
    float* st  = ct + (size_t)LL * 64;
    u16* att = xb;
    u16* vt  = wqkvT;   // dead after fused QKV GEMM

    convert_f32_bf16<<<dim3((unsigned)(SZ_X / 1024)), dim3(256), 0, stream>>>(x, xb, (int)SZ_X);
    // fused transposed weights: rows 0..2047 = wq cols, 2048..3071 = wk, 3072..4095 = wv
    transpose_conv<<<dim3(32, 32), dim3(256), 0, stream>>>(wq, wqkvT, DD, DD);
    transpose_conv<<<dim3(16, 32), dim3(256), 0, stream>>>(wk, wqkvT + (size_t)2048 * DD, DD, KVH * HDIM);
    transpose_conv<<<dim3(16, 32), dim3(256), 0, stream>>>(wv, wqkvT + (size_t)3072 * DD, DD, KVH * HDIM);
    transpose_conv<<<dim3(32, 32), dim3(256), 0, stream>>>(wo, woT, HH * HDIM, DD);
    rope_table<<<dim3(LL * 64 / 256), dim3(256), 0, stream>>>(ct, st);

    // fused QKV projection: [B*L, 4096] = xb @ wqkvT^T
    gemm_bt<false><<<dim3(QKVW / 128, BB * LL / 128), dim3(256), 0, stream>>>(xb, wqkvT, qkv, BB * LL, QKVW, DD);

    rope_norm<<<dim3(BB * LL * (HH + KVH) / 4), dim3(256), 0, stream>>>(qkv, qn, kn, ct, st);
    transpose_v<<<dim3(LL / 64, HDIM / 64, BB * KVH), dim3(256), 0, stream>>>(qkv, vt);

    attn_kernel<<<dim3(LL / 128, BB * HH), dim3(256), 0, stream>>>(qkv, vt, att);
    gemm_bt<true><<<dim3(DD / 128, BB * LL / 128), dim3(256), 0, stream>>>(att, woT, d_out, BB * LL, DD, DD);
}